// Round 1
// baseline (1021.237 us; speedup 1.0000x reference)
//
#include <hip/hip_runtime.h>
#include <math.h>

#define LSEQ 2048
#define DMODEL 256
#define NH 8
#define HD 32
#define TQ 32
#define TK 64

// ---------------- C[4096 x 256] = A[4096 x 256] @ W^T + bias ----------------
// 64x64 tile, 256 threads, 4x4 micro-tile, K-chunk 16, LDS tiles transposed in k.
__global__ __launch_bounds__(256) void gemm_bias_kernel(
    const float* __restrict__ A, const float* __restrict__ W,
    const float* __restrict__ bias, float* __restrict__ C)
{
  __shared__ float At[16][68];
  __shared__ float Wt[16][68];
  const int tid = threadIdx.x;
  const int row0 = blockIdx.x * 64;
  const int col0 = blockIdx.y * 64;
  const int tx = tid & 15, ty = tid >> 4;
  const int lr = tid >> 2;          // 0..63
  const int lc = (tid & 3) * 4;     // 0,4,8,12
  float acc[4][4] = {};
  for (int k0 = 0; k0 < DMODEL; k0 += 16) {
    float4 av = *(const float4*)&A[(row0 + lr) * DMODEL + k0 + lc];
    float4 wv = *(const float4*)&W[(col0 + lr) * DMODEL + k0 + lc];
    __syncthreads();
    At[lc+0][lr] = av.x; At[lc+1][lr] = av.y; At[lc+2][lr] = av.z; At[lc+3][lr] = av.w;
    Wt[lc+0][lr] = wv.x; Wt[lc+1][lr] = wv.y; Wt[lc+2][lr] = wv.z; Wt[lc+3][lr] = wv.w;
    __syncthreads();
#pragma unroll
    for (int kk = 0; kk < 16; ++kk) {
      float4 a4 = *(const float4*)&At[kk][ty*4];
      float4 b4 = *(const float4*)&Wt[kk][tx*4];
      acc[0][0] += a4.x*b4.x; acc[0][1] += a4.x*b4.y; acc[0][2] += a4.x*b4.z; acc[0][3] += a4.x*b4.w;
      acc[1][0] += a4.y*b4.x; acc[1][1] += a4.y*b4.y; acc[1][2] += a4.y*b4.z; acc[1][3] += a4.y*b4.w;
      acc[2][0] += a4.z*b4.x; acc[2][1] += a4.z*b4.y; acc[2][2] += a4.z*b4.z; acc[2][3] += a4.z*b4.w;
      acc[3][0] += a4.w*b4.x; acc[3][1] += a4.w*b4.y; acc[3][2] += a4.w*b4.z; acc[3][3] += a4.w*b4.w;
    }
  }
  float4 b4 = *(const float4*)&bias[col0 + tx*4];
#pragma unroll
  for (int i = 0; i < 4; ++i) {
    int r = row0 + ty*4 + i;
    float4 cv;
    cv.x = acc[i][0] + b4.x; cv.y = acc[i][1] + b4.y;
    cv.z = acc[i][2] + b4.z; cv.w = acc[i][3] + b4.w;
    *(float4*)&C[r * DMODEL + col0 + tx*4] = cv;
  }
}

// ---------------- prior tables: E[h][d]=exp(-d^2/(2(u^2+1e-6))), invZ[h][i] ----------------
__global__ __launch_bounds__(256) void prior_kernel(
    const float* __restrict__ u, float* __restrict__ Eb, float* __restrict__ Zb)
{
  __shared__ float Elds[LSEQ];
  const int h = blockIdx.x;
  const int tid = threadIdx.x;
  float uu = u[h];
  float denom = 2.0f * (uu*uu + 1e-6f);
  for (int d = tid; d < LSEQ; d += 256) {
    float dd = (float)d;
    float e = __expf(-(dd*dd) / denom);
    Elds[d] = e;
    if (blockIdx.y == 0) Eb[h*LSEQ + d] = e;
  }
  __syncthreads();
  int i = blockIdx.y * 256 + tid;
  float sum = 0.f;
  for (int j = 0; j < LSEQ; ++j) {
    int dist = (i >= j) ? (i - j) : (j - i);
    sum += Elds[dist];
  }
  Zb[h*LSEQ + i] = 1.0f / (sum + 1e-6f);
}

// ---------------- flash attention + discrepancy ----------------
// grid (L/TQ, NH, B); 256 threads: tq = tid>>3 (q row 0..31), tk = tid&7 (k group).
// Two-pass online softmax: pass1 computes m,l streaming K; pass2 recomputes scores,
// accumulates O += p*V and per-key |p - prior| sums into LDS, then global atomics.
__global__ __launch_bounds__(256) void attn_kernel(
    const float* __restrict__ Qm, const float* __restrict__ Km, const float* __restrict__ Vm,
    const float* __restrict__ Eb, const float* __restrict__ Zb,
    float* __restrict__ Om, float* __restrict__ disc)
{
  __shared__ float Kt[TK][36];   // pad 36: conflict-free b128 with j = tk + 8*jj
  __shared__ float Vt[TK][36];
  __shared__ float Elds[LSEQ];
  __shared__ float dcol[LSEQ];
  __shared__ float Qs[TQ][36];
  __shared__ float mred[TQ][9];
  __shared__ float lred[TQ][9];
  __shared__ float mrow[TQ];
  __shared__ float lrow[TQ];
  __shared__ float izrow[TQ];
  __shared__ float obuf[TQ][HD];

  const int tid = threadIdx.x;
  const int q0 = blockIdx.x * TQ;
  const int h  = blockIdx.y;
  const int b  = blockIdx.z;
  const int tq = tid >> 3;
  const int tk = tid & 7;
  const float scale = 0.17677669529663687f;  // 1/sqrt(32)

  for (int d = tid; d < LSEQ; d += 256) { Elds[d] = Eb[h*LSEQ + d]; dcol[d] = 0.f; }
  for (int idx = tid; idx < TQ*HD; idx += 256) ((float*)obuf)[idx] = 0.f;
  if (tid < TQ) izrow[tid] = Zb[h*LSEQ + q0 + tid];
  {
    int r = tid >> 3, c4 = (tid & 7) * 4;
    float4 qv = *(const float4*)&Qm[(b*LSEQ + q0 + r) * DMODEL + h*HD + c4];
    Qs[r][c4+0] = qv.x * scale; Qs[r][c4+1] = qv.y * scale;
    Qs[r][c4+2] = qv.z * scale; Qs[r][c4+3] = qv.w * scale;
  }
  __syncthreads();

  float4 qreg[8];
#pragma unroll
  for (int ee = 0; ee < 8; ++ee) qreg[ee] = *(const float4*)&Qs[tq][ee*4];

  // ---- pass 1: online m, l over this thread's k-slice ----
  float m_t = -1e30f, l_t = 0.f;
  for (int kt = 0; kt < LSEQ; kt += TK) {
#pragma unroll
    for (int i = 0; i < 2; ++i) {
      int fid = tid + i*256;
      int j = fid >> 3, c4 = (fid & 7)*4;
      *(float4*)&Kt[j][c4] = *(const float4*)&Km[(b*LSEQ + kt + j) * DMODEL + h*HD + c4];
    }
    __syncthreads();
    float s[8];
    float mloc = -1e30f;
#pragma unroll
    for (int jj = 0; jj < 8; ++jj) {
      int j = tk + jj*8;
      const float4* kr = (const float4*)&Kt[j][0];
      float acc = 0.f;
#pragma unroll
      for (int ee = 0; ee < 8; ++ee) {
        float4 kv = kr[ee];
        acc += qreg[ee].x*kv.x + qreg[ee].y*kv.y + qreg[ee].z*kv.z + qreg[ee].w*kv.w;
      }
      s[jj] = acc;
      mloc = fmaxf(mloc, acc);
    }
    float mnew = fmaxf(m_t, mloc);
    float sum = 0.f;
#pragma unroll
    for (int jj = 0; jj < 8; ++jj) sum += __expf(s[jj] - mnew);
    l_t = l_t * __expf(m_t - mnew) + sum;
    m_t = mnew;
    __syncthreads();
  }

  // reduce m,l across the 8 tk threads of each row
  mred[tq][tk] = m_t;
  lred[tq][tk] = l_t;
  __syncthreads();
  if (tk == 0) {
    float m = mred[tq][0];
#pragma unroll
    for (int t = 1; t < 8; ++t) m = fmaxf(m, mred[tq][t]);
    float l = 0.f;
#pragma unroll
    for (int t = 0; t < 8; ++t) l += lred[tq][t] * __expf(mred[tq][t] - m);
    mrow[tq] = m;
    lrow[tq] = l;
  }
  __syncthreads();
  const float mfin = mrow[tq];
  const float linv = 1.0f / lrow[tq];
  const float iz   = izrow[tq];
  const int   qg   = q0 + tq;

  // ---- pass 2: final p, O accumulation, discrepancy column sums ----
  float4 oacc[8];
#pragma unroll
  for (int ee = 0; ee < 8; ++ee) oacc[ee] = make_float4(0.f, 0.f, 0.f, 0.f);

  for (int kt = 0; kt < LSEQ; kt += TK) {
#pragma unroll
    for (int i = 0; i < 2; ++i) {
      int fid = tid + i*256;
      int j = fid >> 3, c4 = (fid & 7)*4;
      *(float4*)&Kt[j][c4] = *(const float4*)&Km[(b*LSEQ + kt + j) * DMODEL + h*HD + c4];
      *(float4*)&Vt[j][c4] = *(const float4*)&Vm[(b*LSEQ + kt + j) * DMODEL + h*HD + c4];
    }
    __syncthreads();
#pragma unroll
    for (int jj = 0; jj < 8; ++jj) {
      int j = tk + jj*8;
      const float4* kr = (const float4*)&Kt[j][0];
      float acc = 0.f;
#pragma unroll
      for (int ee = 0; ee < 8; ++ee) {
        float4 kv = kr[ee];
        acc += qreg[ee].x*kv.x + qreg[ee].y*kv.y + qreg[ee].z*kv.z + qreg[ee].w*kv.w;
      }
      float p = __expf(acc - mfin) * linv;
      int jg = kt + j;
      int dist = (qg >= jg) ? (qg - jg) : (jg - qg);
      float dv = fabsf(p - Elds[dist] * iz);
      // sum over the 8 tq-rows this wave holds for (tk, jj): lanes {tk, tk+8, ..., tk+56}
      dv += __shfl_xor(dv, 8);
      dv += __shfl_xor(dv, 16);
      dv += __shfl_xor(dv, 32);
      if ((tid & 56) == 0) atomicAdd(&dcol[jg], dv);
      const float4* vr = (const float4*)&Vt[j][0];
#pragma unroll
      for (int ee = 0; ee < 8; ++ee) {
        float4 vv = vr[ee];
        oacc[ee].x += p * vv.x; oacc[ee].y += p * vv.y;
        oacc[ee].z += p * vv.z; oacc[ee].w += p * vv.w;
      }
    }
    __syncthreads();
  }

  // reduce O across tk via LDS atomics (once per block)
#pragma unroll
  for (int ee = 0; ee < 8; ++ee) {
    atomicAdd(&obuf[tq][ee*4+0], oacc[ee].x);
    atomicAdd(&obuf[tq][ee*4+1], oacc[ee].y);
    atomicAdd(&obuf[tq][ee*4+2], oacc[ee].z);
    atomicAdd(&obuf[tq][ee*4+3], oacc[ee].w);
  }
  __syncthreads();
  {
    int r = tid >> 3, c4 = (tid & 7) * 4;
    float4 ov = *(const float4*)&obuf[r][c4];
    *(float4*)&Om[(b*LSEQ + q0 + r) * DMODEL + h*HD + c4] = ov;
  }
  const float sc = 1.0f / (float)(NH * LSEQ);
  for (int idx = tid; idx < LSEQ; idx += 256) {
    atomicAdd(&disc[b*LSEQ + idx], dcol[idx] * sc);
  }
}

extern "C" void kernel_launch(void* const* d_in, const int* in_sizes, int n_in,
                              void* d_out, int out_size, void* d_ws, size_t ws_size,
                              hipStream_t stream)
{
  const float* x  = (const float*)d_in[0];
  const float* Wq = (const float*)d_in[1];
  const float* bq = (const float*)d_in[2];
  const float* Wk = (const float*)d_in[3];
  const float* bk = (const float*)d_in[4];
  const float* Wv = (const float*)d_in[5];
  const float* bv = (const float*)d_in[6];
  const float* u  = (const float*)d_in[7];
  const float* Wo = (const float*)d_in[8];
  const float* bo = (const float*)d_in[9];

  float* out  = (float*)d_out;
  float* disc = out + (size_t)2 * LSEQ * DMODEL;

  float* ws = (float*)d_ws;
  float* Qb = ws;                    // 2*2048*256 = 1048576
  float* Kb = Qb + 1048576;
  float* Vb = Kb + 1048576;
  float* Ob = Vb + 1048576;
  float* Eb = Ob + 1048576;          // 8*2048
  float* Zb = Eb + NH * LSEQ;        // 8*2048

  hipMemsetAsync(disc, 0, (size_t)2 * LSEQ * sizeof(float), stream);

  dim3 gproj(64, 4, 1);
  gemm_bias_kernel<<<gproj, 256, 0, stream>>>(x, Wq, bq, Qb);
  gemm_bias_kernel<<<gproj, 256, 0, stream>>>(x, Wk, bk, Kb);
  gemm_bias_kernel<<<gproj, 256, 0, stream>>>(x, Wv, bv, Vb);
  prior_kernel<<<dim3(NH, 8), 256, 0, stream>>>(u, Eb, Zb);
  attn_kernel<<<dim3(LSEQ / TQ, NH, 2), 256, 0, stream>>>(Qb, Kb, Vb, Eb, Zb, Ob, disc);
  gemm_bias_kernel<<<gproj, 256, 0, stream>>>(Ob, Wo, bo, out);
}

// Round 2
// 277.280 us; speedup vs baseline: 3.6831x; 3.6831x over previous
//
#include <hip/hip_runtime.h>
#include <hip/hip_bf16.h>
#include <math.h>

#define LSEQ 2048
#define DMODEL 256
#define NH 8
#define HD 32
#define TK 64

typedef __attribute__((ext_vector_type(8))) short bf16x8;
typedef __attribute__((ext_vector_type(4))) float f32x4;

__device__ __forceinline__ short f2bf(float x) {
  __hip_bfloat16 h = __float2bfloat16(x);
  return __builtin_bit_cast(short, h);
}
__device__ __forceinline__ float bf2f(short s) {
  __hip_bfloat16 h = __builtin_bit_cast(__hip_bfloat16, s);
  return __bfloat162float(h);
}

// ---------------- C[4096 x 256] = A[4096 x 256] @ W^T + bias ----------------
__global__ __launch_bounds__(256) void gemm_bias_kernel(
    const float* __restrict__ A, const float* __restrict__ W,
    const float* __restrict__ bias, float* __restrict__ C)
{
  __shared__ float At[16][68];
  __shared__ float Wt[16][68];
  const int tid = threadIdx.x;
  const int row0 = blockIdx.x * 64;
  const int col0 = blockIdx.y * 64;
  const int tx = tid & 15, ty = tid >> 4;
  const int lr = tid >> 2;
  const int lc = (tid & 3) * 4;
  float acc[4][4] = {};
  for (int k0 = 0; k0 < DMODEL; k0 += 16) {
    float4 av = *(const float4*)&A[(row0 + lr) * DMODEL + k0 + lc];
    float4 wv = *(const float4*)&W[(col0 + lr) * DMODEL + k0 + lc];
    __syncthreads();
    At[lc+0][lr] = av.x; At[lc+1][lr] = av.y; At[lc+2][lr] = av.z; At[lc+3][lr] = av.w;
    Wt[lc+0][lr] = wv.x; Wt[lc+1][lr] = wv.y; Wt[lc+2][lr] = wv.z; Wt[lc+3][lr] = wv.w;
    __syncthreads();
#pragma unroll
    for (int kk = 0; kk < 16; ++kk) {
      float4 a4 = *(const float4*)&At[kk][ty*4];
      float4 b4 = *(const float4*)&Wt[kk][tx*4];
      acc[0][0] += a4.x*b4.x; acc[0][1] += a4.x*b4.y; acc[0][2] += a4.x*b4.z; acc[0][3] += a4.x*b4.w;
      acc[1][0] += a4.y*b4.x; acc[1][1] += a4.y*b4.y; acc[1][2] += a4.y*b4.z; acc[1][3] += a4.y*b4.w;
      acc[2][0] += a4.z*b4.x; acc[2][1] += a4.z*b4.y; acc[2][2] += a4.z*b4.z; acc[2][3] += a4.z*b4.w;
      acc[3][0] += a4.w*b4.x; acc[3][1] += a4.w*b4.y; acc[3][2] += a4.w*b4.z; acc[3][3] += a4.w*b4.w;
    }
  }
  float4 b4 = *(const float4*)&bias[col0 + tx*4];
#pragma unroll
  for (int i = 0; i < 4; ++i) {
    int r = row0 + ty*4 + i;
    float4 cv;
    cv.x = acc[i][0] + b4.x; cv.y = acc[i][1] + b4.y;
    cv.z = acc[i][2] + b4.z; cv.w = acc[i][3] + b4.w;
    *(float4*)&C[r * DMODEL + col0 + tx*4] = cv;
  }
}

// ---------------- prior tables ----------------
__global__ __launch_bounds__(256) void prior_kernel(
    const float* __restrict__ u, float* __restrict__ Eb, float* __restrict__ Zb)
{
  __shared__ float Elds[LSEQ];
  const int h = blockIdx.x;
  const int tid = threadIdx.x;
  float uu = u[h];
  float denom = 2.0f * (uu*uu + 1e-6f);
  for (int d = tid; d < LSEQ; d += 256) {
    float dd = (float)d;
    float e = __expf(-(dd*dd) / denom);
    Elds[d] = e;
    if (blockIdx.y == 0) Eb[h*LSEQ + d] = e;
  }
  __syncthreads();
  int i = blockIdx.y * 256 + tid;
  float sum = 0.f;
  for (int j = 0; j < LSEQ; ++j) {
    int dist = (i >= j) ? (i - j) : (j - i);
    sum += Elds[dist];
  }
  Zb[h*LSEQ + i] = 1.0f / (sum + 1e-6f);
}

// ---------------- MFMA flash attention + discrepancy ----------------
// grid (L/64, NH, B); 256 threads = 4 waves, each wave owns 16 q rows.
// Split-precision QK (Qh*Kh + Ql*Kh + Qh*Kl) for fp32-grade scores; bf16 PV.
// No-max softmax (scores bounded): pass1 accumulates per-lane partial row sums
// of exp(s); one shuffle-reduce at the end gives linv in registers (C-layout
// rows match between passes). Pass2: p, |p-prior| column sums, P->LDS->A-frag,
// O += P*V via MFMA.
__global__ __launch_bounds__(256) void attn_kernel(
    const float* __restrict__ Qm, const float* __restrict__ Km, const float* __restrict__ Vm,
    const float* __restrict__ Eb, const float* __restrict__ Zb,
    float* __restrict__ Om, float* __restrict__ disc)
{
  __shared__ short Kh[TK][40];        // rows 80B: 16B-aligned b128 frags
  __shared__ short Kl[TK][40];
  __shared__ short Vt[HD][TK + 8];    // V transposed [d][k], rows 144B
  __shared__ short Pt[4][16][40];     // per-wave P tile [q][k], rows 80B
  __shared__ float Elds[LSEQ];
  __shared__ float dcol[LSEQ];

  const int tid  = threadIdx.x;
  const int w    = tid >> 6;
  const int lane = tid & 63;
  const int l15  = lane & 15;
  const int q4   = lane >> 4;
  const int q0   = blockIdx.x * 64;
  const int h    = blockIdx.y;
  const int b    = blockIdx.z;
  const float scale = 0.17677669529663687f;  // 1/sqrt(32)

  for (int i = tid; i < LSEQ; i += 256) { Elds[i] = Eb[h*LSEQ + i]; dcol[i] = 0.f; }

  // ---- Q fragments (A-layout: row=l15, k=(q4)*8+j), scale folded pre-split ----
  bf16x8 qh, ql;
  {
    const int qrow = q0 + w*16 + l15;
    const float* qp = &Qm[((size_t)b*LSEQ + qrow)*DMODEL + h*HD + q4*8];
    float4 a = *(const float4*)qp;
    float4 c = *(const float4*)(qp + 4);
    float qs[8] = {a.x,a.y,a.z,a.w,c.x,c.y,c.z,c.w};
#pragma unroll
    for (int j = 0; j < 8; ++j) {
      float v = qs[j] * scale;
      short hi = f2bf(v);
      qh[j] = hi;
      ql[j] = f2bf(v - bf2f(hi));
    }
  }
  // prior inverse-normalizer for this lane's C-layout rows (row = q4*4+r)
  float iz[4];
#pragma unroll
  for (int r = 0; r < 4; ++r) iz[r] = Zb[h*LSEQ + q0 + w*16 + q4*4 + r];

  // ---- pass 1: l = sum_k exp(s) ----
  float lac[4] = {0.f, 0.f, 0.f, 0.f};
  for (int kt = 0; kt < LSEQ; kt += TK) {
    __syncthreads();
    {
      int r = tid >> 2, c8 = (tid & 3) * 8;
      const float* kp = &Km[((size_t)b*LSEQ + kt + r)*DMODEL + h*HD + c8];
      float4 a = *(const float4*)kp;
      float4 c = *(const float4*)(kp + 4);
      float kv[8] = {a.x,a.y,a.z,a.w,c.x,c.y,c.z,c.w};
      bf16x8 khv, klv;
#pragma unroll
      for (int j = 0; j < 8; ++j) {
        short hi = f2bf(kv[j]);
        khv[j] = hi;
        klv[j] = f2bf(kv[j] - bf2f(hi));
      }
      *(bf16x8*)&Kh[r][c8] = khv;
      *(bf16x8*)&Kl[r][c8] = klv;
    }
    __syncthreads();
#pragma unroll
    for (int st = 0; st < 4; ++st) {
      bf16x8 kbh = *(bf16x8*)&Kh[st*16 + l15][q4*8];
      bf16x8 kbl = *(bf16x8*)&Kl[st*16 + l15][q4*8];
      f32x4 s = {0.f, 0.f, 0.f, 0.f};
      s = __builtin_amdgcn_mfma_f32_16x16x32_bf16(qh, kbh, s, 0, 0, 0);
      s = __builtin_amdgcn_mfma_f32_16x16x32_bf16(ql, kbh, s, 0, 0, 0);
      s = __builtin_amdgcn_mfma_f32_16x16x32_bf16(qh, kbl, s, 0, 0, 0);
#pragma unroll
      for (int r = 0; r < 4; ++r) lac[r] += __expf(s[r]);
    }
  }
  float linv[4];
#pragma unroll
  for (int r = 0; r < 4; ++r) {
    float v = lac[r];
    v += __shfl_xor(v, 1);
    v += __shfl_xor(v, 2);
    v += __shfl_xor(v, 4);
    v += __shfl_xor(v, 8);
    linv[r] = 1.0f / v;
  }

  // ---- pass 2: p, discrepancy, O += P*V ----
  f32x4 oacc[2] = {{0.f,0.f,0.f,0.f},{0.f,0.f,0.f,0.f}};
  for (int kt = 0; kt < LSEQ; kt += TK) {
    __syncthreads();
    {
      int r = tid >> 2, c8 = (tid & 3) * 8;
      const float* kp = &Km[((size_t)b*LSEQ + kt + r)*DMODEL + h*HD + c8];
      const float* vp = &Vm[((size_t)b*LSEQ + kt + r)*DMODEL + h*HD + c8];
      float4 a  = *(const float4*)kp;
      float4 c  = *(const float4*)(kp + 4);
      float4 va = *(const float4*)vp;
      float4 vc = *(const float4*)(vp + 4);
      float kv[8] = {a.x,a.y,a.z,a.w,c.x,c.y,c.z,c.w};
      float vv[8] = {va.x,va.y,va.z,va.w,vc.x,vc.y,vc.z,vc.w};
      bf16x8 khv, klv;
#pragma unroll
      for (int j = 0; j < 8; ++j) {
        short hi = f2bf(kv[j]);
        khv[j] = hi;
        klv[j] = f2bf(kv[j] - bf2f(hi));
      }
      *(bf16x8*)&Kh[r][c8] = khv;
      *(bf16x8*)&Kl[r][c8] = klv;
#pragma unroll
      for (int j = 0; j < 8; ++j) Vt[c8 + j][r] = f2bf(vv[j]);
    }
    __syncthreads();
#pragma unroll
    for (int st = 0; st < 4; ++st) {
      bf16x8 kbh = *(bf16x8*)&Kh[st*16 + l15][q4*8];
      bf16x8 kbl = *(bf16x8*)&Kl[st*16 + l15][q4*8];
      f32x4 s = {0.f, 0.f, 0.f, 0.f};
      s = __builtin_amdgcn_mfma_f32_16x16x32_bf16(qh, kbh, s, 0, 0, 0);
      s = __builtin_amdgcn_mfma_f32_16x16x32_bf16(ql, kbh, s, 0, 0, 0);
      s = __builtin_amdgcn_mfma_f32_16x16x32_bf16(qh, kbl, s, 0, 0, 0);
      const int kg = kt + st*16 + l15;
      float dsum = 0.f;
#pragma unroll
      for (int r = 0; r < 4; ++r) {
        float p = __expf(s[r]) * linv[r];
        int qg = q0 + w*16 + q4*4 + r;
        int dist = (qg >= kg) ? (qg - kg) : (kg - qg);
        dsum += fabsf(p - Elds[dist] * iz[r]);
        Pt[w][q4*4 + r][st*16 + l15] = f2bf(p);
      }
      dsum += __shfl_xor(dsum, 16);
      dsum += __shfl_xor(dsum, 32);
      if (q4 == 0) atomicAdd(&dcol[kg], dsum);
      if (st & 1) {
        const int kc = st >> 1;
        bf16x8 pa = *(bf16x8*)&Pt[w][l15][kc*32 + q4*8];
#pragma unroll
        for (int dt = 0; dt < 2; ++dt) {
          bf16x8 vb = *(bf16x8*)&Vt[dt*16 + l15][kc*32 + q4*8];
          oacc[dt] = __builtin_amdgcn_mfma_f32_16x16x32_bf16(pa, vb, oacc[dt], 0, 0, 0);
        }
      }
    }
  }

  // ---- epilogue: O store (C-layout) + discrepancy flush ----
#pragma unroll
  for (int dt = 0; dt < 2; ++dt)
#pragma unroll
    for (int r = 0; r < 4; ++r)
      Om[((size_t)b*LSEQ + q0 + w*16 + q4*4 + r)*DMODEL + h*HD + dt*16 + l15] = oacc[dt][r];

  __syncthreads();
  const float sc = 1.0f / (float)(NH * LSEQ);
  for (int i = tid; i < LSEQ; i += 256)
    atomicAdd(&disc[(size_t)b*LSEQ + i], dcol[i] * sc);
}

extern "C" void kernel_launch(void* const* d_in, const int* in_sizes, int n_in,
                              void* d_out, int out_size, void* d_ws, size_t ws_size,
                              hipStream_t stream)
{
  const float* x  = (const float*)d_in[0];
  const float* Wq = (const float*)d_in[1];
  const float* bq = (const float*)d_in[2];
  const float* Wk = (const float*)d_in[3];
  const float* bk = (const float*)d_in[4];
  const float* Wv = (const float*)d_in[5];
  const float* bv = (const float*)d_in[6];
  const float* u  = (const float*)d_in[7];
  const float* Wo = (const float*)d_in[8];
  const float* bo = (const float*)d_in[9];

  float* out  = (float*)d_out;
  float* disc = out + (size_t)2 * LSEQ * DMODEL;

  float* ws = (float*)d_ws;
  float* Qb = ws;
  float* Kb = Qb + 1048576;
  float* Vb = Kb + 1048576;
  float* Ob = Vb + 1048576;
  float* Eb = Ob + 1048576;
  float* Zb = Eb + NH * LSEQ;

  hipMemsetAsync(disc, 0, (size_t)2 * LSEQ * sizeof(float), stream);

  dim3 gproj(64, 4, 1);
  gemm_bias_kernel<<<gproj, 256, 0, stream>>>(x, Wq, bq, Qb);
  gemm_bias_kernel<<<gproj, 256, 0, stream>>>(x, Wk, bk, Kb);
  gemm_bias_kernel<<<gproj, 256, 0, stream>>>(x, Wv, bv, Vb);
  prior_kernel<<<dim3(NH, 8), 256, 0, stream>>>(u, Eb, Zb);
  attn_kernel<<<dim3(LSEQ / 64, NH, 2), 256, 0, stream>>>(Qb, Kb, Vb, Eb, Zb, Ob, disc);
  gemm_bias_kernel<<<gproj, 256, 0, stream>>>(Ob, Wo, bo, out);
}

// Round 3
// 214.176 us; speedup vs baseline: 4.7682x; 1.2946x over previous
//
#include <hip/hip_runtime.h>
#include <hip/hip_bf16.h>
#include <math.h>

#define LSEQ 2048
#define DMODEL 256
#define NH 8
#define HD 32

typedef __attribute__((ext_vector_type(8))) short bf16x8;
typedef __attribute__((ext_vector_type(4))) float f32x4;

#define MFMA __builtin_amdgcn_mfma_f32_16x16x32_bf16

__device__ __forceinline__ short f2bf(float x) {
  __hip_bfloat16 h = __float2bfloat16(x);
  return __builtin_bit_cast(short, h);
}
__device__ __forceinline__ float bf2f(short s) {
  __hip_bfloat16 h = __builtin_bit_cast(__hip_bfloat16, s);
  return __bfloat162float(h);
}

// ---------------- fp32 -> split bf16 conversion of x, Wq|Wk|Wv (concat), Wo ----
__global__ __launch_bounds__(256) void convert_kernel(
    const float* __restrict__ x, const float* __restrict__ Wq,
    const float* __restrict__ Wk, const float* __restrict__ Wv,
    const float* __restrict__ Wo,
    short* __restrict__ xh, short* __restrict__ xl,
    short* __restrict__ Wch, short* __restrict__ Wcl,
    short* __restrict__ Woh, short* __restrict__ Wol)
{
  const int t = blockIdx.x * 256 + threadIdx.x;   // 0..327679
  const int i4 = t * 4;
  const float* src; short* dh; short* dl;
  if (i4 < 1048576) { src = x + i4; dh = xh + i4; dl = xl + i4; }
  else if (i4 < 1245184) {
    int j = i4 - 1048576; int row = j >> 8; int col = j & 255;
    const float* W = (row < 256) ? Wq : (row < 512) ? Wk : Wv;
    src = W + (row & 255) * 256 + col; dh = Wch + j; dl = Wcl + j;
  } else {
    int j = i4 - 1245184; src = Wo + j; dh = Woh + j; dl = Wol + j;
  }
  float4 v = *(const float4*)src;
  short h0 = f2bf(v.x), h1 = f2bf(v.y), h2 = f2bf(v.z), h3 = f2bf(v.w);
  short4 hv = make_short4(h0, h1, h2, h3);
  short4 lv = make_short4(f2bf(v.x - bf2f(h0)), f2bf(v.y - bf2f(h1)),
                          f2bf(v.z - bf2f(h2)), f2bf(v.w - bf2f(h3)));
  *(short4*)dh = hv;
  *(short4*)dl = lv;
}

// ---------------- prior tables via prefix sum: Z(i) = C(i)+C(L-1-i)-E0 --------
__global__ __launch_bounds__(256) void prior_kernel(
    const float* __restrict__ u, float* __restrict__ Eb, float* __restrict__ Zb)
{
  __shared__ float Cs[LSEQ];
  __shared__ float part[256];
  const int h = blockIdx.x, tid = threadIdx.x;
  const float uu = u[h];
  const float den = 2.0f * (uu * uu + 1e-6f);
  float e[8]; float run = 0.f;
  const int base = tid * 8;
#pragma unroll
  for (int j = 0; j < 8; ++j) {
    float d = (float)(base + j);
    e[j] = __expf(-(d * d) / den);
    run += e[j];
  }
  part[tid] = run;
  __syncthreads();
  for (int off = 1; off < 256; off <<= 1) {
    float v = (tid >= off) ? part[tid - off] : 0.f;
    __syncthreads();
    part[tid] += v;
    __syncthreads();
  }
  float c = part[tid] - run;  // exclusive prefix
#pragma unroll
  for (int j = 0; j < 8; ++j) {
    c += e[j];
    Cs[base + j] = c;                 // inclusive cumsum C[d]
    Eb[h * LSEQ + base + j] = e[j];
  }
  __syncthreads();
  const float E0 = Cs[0];
  for (int i = tid; i < LSEQ; i += 256) {
    float s = Cs[i] + Cs[LSEQ - 1 - i] - E0;
    Zb[h * LSEQ + i] = 1.0f / (s + 1e-6f);
  }
}

// ---------------- fused QKV GEMM (split-bf16 MFMA, LDS-free) -----------------
// C[4096 x 768] = x @ [Wq;Wk;Wv]^T + b. Epilogue: Q,K -> split bf16 row-major;
// V -> bf16 transposed [bh][d][k].
__global__ __launch_bounds__(256) void qkv_gemm(
    const short* __restrict__ Ah, const short* __restrict__ Al,
    const short* __restrict__ Bh, const short* __restrict__ Bl,
    const float* __restrict__ bq, const float* __restrict__ bk,
    const float* __restrict__ bv,
    short* __restrict__ Qh, short* __restrict__ Ql,
    short* __restrict__ Kh, short* __restrict__ Kl,
    short* __restrict__ Vt)
{
  const int tid = threadIdx.x, w = tid >> 6, lane = tid & 63;
  const int l15 = lane & 15, q4 = lane >> 4;
  const int m0 = blockIdx.x * 64, n0 = blockIdx.y * 64;
  const int mrow = m0 + w * 16 + l15;
  f32x4 acc[4] = {{0,0,0,0},{0,0,0,0},{0,0,0,0},{0,0,0,0}};
  for (int k0 = 0; k0 < 256; k0 += 32) {
    bf16x8 ah = *(const bf16x8*)&Ah[(size_t)mrow * 256 + k0 + q4 * 8];
    bf16x8 al = *(const bf16x8*)&Al[(size_t)mrow * 256 + k0 + q4 * 8];
#pragma unroll
    for (int nt = 0; nt < 4; ++nt) {
      const size_t bi = (size_t)(n0 + nt * 16 + l15) * 256 + k0 + q4 * 8;
      bf16x8 bh = *(const bf16x8*)&Bh[bi];
      bf16x8 bl = *(const bf16x8*)&Bl[bi];
      acc[nt] = MFMA(ah, bh, acc[nt], 0, 0, 0);
      acc[nt] = MFMA(al, bh, acc[nt], 0, 0, 0);
      acc[nt] = MFMA(ah, bl, acc[nt], 0, 0, 0);
    }
  }
  const int type = n0 >> 8;        // 0=Q 1=K 2=V
  const int n0l = n0 & 255;
  const float* bias = (type == 0) ? bq : (type == 1) ? bk : bv;
#pragma unroll
  for (int nt = 0; nt < 4; ++nt) {
    const int col = n0l + nt * 16 + l15;
    const float bvv = bias[col];
#pragma unroll
    for (int r = 0; r < 4; ++r) {
      const int m = m0 + w * 16 + q4 * 4 + r;
      float v = acc[nt][r] + bvv;
      if (type == 2) {
        Vt[((size_t)((m >> 11) * 8 + (col >> 5)) * 32 + (col & 31)) * 2048 + (m & 2047)] = f2bf(v);
      } else if (type == 0) {
        short hi = f2bf(v);
        Qh[(size_t)m * 256 + col] = hi;
        Ql[(size_t)m * 256 + col] = f2bf(v - bf2f(hi));
      } else {
        short hi = f2bf(v);
        Kh[(size_t)m * 256 + col] = hi;
        Kl[(size_t)m * 256 + col] = f2bf(v - bf2f(hi));
      }
    }
  }
}

// ---------------- output GEMM (split-bf16 MFMA, fp32 out) --------------------
__global__ __launch_bounds__(256) void out_gemm(
    const short* __restrict__ Ah, const short* __restrict__ Al,
    const short* __restrict__ Bh, const short* __restrict__ Bl,
    const float* __restrict__ bias, float* __restrict__ C)
{
  const int tid = threadIdx.x, w = tid >> 6, lane = tid & 63;
  const int l15 = lane & 15, q4 = lane >> 4;
  const int m0 = blockIdx.x * 64, n0 = blockIdx.y * 64;
  const int mrow = m0 + w * 16 + l15;
  f32x4 acc[4] = {{0,0,0,0},{0,0,0,0},{0,0,0,0},{0,0,0,0}};
  for (int k0 = 0; k0 < 256; k0 += 32) {
    bf16x8 ah = *(const bf16x8*)&Ah[(size_t)mrow * 256 + k0 + q4 * 8];
    bf16x8 al = *(const bf16x8*)&Al[(size_t)mrow * 256 + k0 + q4 * 8];
#pragma unroll
    for (int nt = 0; nt < 4; ++nt) {
      const size_t bi = (size_t)(n0 + nt * 16 + l15) * 256 + k0 + q4 * 8;
      bf16x8 bh = *(const bf16x8*)&Bh[bi];
      bf16x8 bl = *(const bf16x8*)&Bl[bi];
      acc[nt] = MFMA(ah, bh, acc[nt], 0, 0, 0);
      acc[nt] = MFMA(al, bh, acc[nt], 0, 0, 0);
      acc[nt] = MFMA(ah, bl, acc[nt], 0, 0, 0);
    }
  }
#pragma unroll
  for (int nt = 0; nt < 4; ++nt) {
    const int col = n0 + nt * 16 + l15;
    const float bvv = bias[col];
#pragma unroll
    for (int r = 0; r < 4; ++r) {
      const int m = m0 + w * 16 + q4 * 4 + r;
      C[(size_t)m * 256 + col] = acc[nt][r] + bvv;
    }
  }
}

// ---------------- barrier-free MFMA flash attention + discrepancy ------------
// grid (L/64, NH, B); 256 threads = 4 waves: wave = (qg = w>>1 -> 32 q rows,
// sh = w&1 -> k-column half). All Q/K/V fragments are direct contiguous global
// b128 loads (no LDS staging, no barriers in the K-loop). Pt: wave-private LDS
// round-trip (C-layout -> A-layout). 3 barriers total (init, l-reduce, epilogue).
__global__ __launch_bounds__(256) void attn_kernel(
    const short* __restrict__ Qhb, const short* __restrict__ Qlb,
    const short* __restrict__ Khb, const short* __restrict__ Klb,
    const short* __restrict__ Vtb,
    const float* __restrict__ Eb, const float* __restrict__ Zb,
    short* __restrict__ Ohb, short* __restrict__ Olb,
    float* __restrict__ disc)
{
  __shared__ short Pt[4][32][40];   // per-wave P tile [q32][k32], rows 80B
  __shared__ float Elds[LSEQ];
  __shared__ float dcol[LSEQ];
  __shared__ float lpart[4][32];

  const int tid = threadIdx.x, w = tid >> 6, lane = tid & 63;
  const int l15 = lane & 15, q4 = lane >> 4;
  const int qg = w >> 1, sh = w & 1;
  const int q0 = blockIdx.x * 64;
  const int h = blockIdx.y, b = blockIdx.z;
  const int bh = b * NH + h;
  const float scale = 0.17677669529663687f;  // 1/sqrt(32)

  for (int i = tid; i < LSEQ; i += 256) { Elds[i] = Eb[h * LSEQ + i]; dcol[i] = 0.f; }

  bf16x8 qh[2], ql[2];
  float iz[2][4];
#pragma unroll
  for (int rg = 0; rg < 2; ++rg) {
    const size_t qoff = ((size_t)b * LSEQ + q0 + qg * 32 + rg * 16 + l15) * DMODEL + h * HD + q4 * 8;
    qh[rg] = *(const bf16x8*)&Qhb[qoff];
    ql[rg] = *(const bf16x8*)&Qlb[qoff];
#pragma unroll
    for (int r = 0; r < 4; ++r)
      iz[rg][r] = Zb[h * LSEQ + q0 + qg * 32 + rg * 16 + q4 * 4 + r];
  }
  __syncthreads();

  // ---- pass 1: per-lane partial row sums of exp(s) ----
  float lac[2][4] = {{0,0,0,0},{0,0,0,0}};
  for (int kt = 0; kt < LSEQ; kt += 64) {
#pragma unroll
    for (int s2 = 0; s2 < 2; ++s2) {
      const int st = sh * 2 + s2;
      const size_t koff = ((size_t)b * LSEQ + kt + st * 16 + l15) * DMODEL + h * HD + q4 * 8;
      bf16x8 kbh = *(const bf16x8*)&Khb[koff];
      bf16x8 kbl = *(const bf16x8*)&Klb[koff];
#pragma unroll
      for (int rg = 0; rg < 2; ++rg) {
        f32x4 s = {0.f, 0.f, 0.f, 0.f};
        s = MFMA(qh[rg], kbh, s, 0, 0, 0);
        s = MFMA(ql[rg], kbh, s, 0, 0, 0);
        s = MFMA(qh[rg], kbl, s, 0, 0, 0);
#pragma unroll
        for (int r = 0; r < 4; ++r) lac[rg][r] += __expf(s[r] * scale);
      }
    }
  }
#pragma unroll
  for (int rg = 0; rg < 2; ++rg)
#pragma unroll
    for (int r = 0; r < 4; ++r) {
      float v = lac[rg][r];
      v += __shfl_xor(v, 1); v += __shfl_xor(v, 2);
      v += __shfl_xor(v, 4); v += __shfl_xor(v, 8);
      lac[rg][r] = v;
    }
  if (l15 == 0) {
#pragma unroll
    for (int rg = 0; rg < 2; ++rg)
#pragma unroll
      for (int r = 0; r < 4; ++r) lpart[w][rg * 16 + q4 * 4 + r] = lac[rg][r];
  }
  __syncthreads();
  float linv[2][4];
#pragma unroll
  for (int rg = 0; rg < 2; ++rg)
#pragma unroll
    for (int r = 0; r < 4; ++r)
      linv[rg][r] = 1.0f / (lpart[qg * 2][rg * 16 + q4 * 4 + r] +
                            lpart[qg * 2 + 1][rg * 16 + q4 * 4 + r]);

  // ---- pass 2: p, discrepancy column sums, O += P*V ----
  f32x4 oacc[2][2] = {{{0,0,0,0},{0,0,0,0}},{{0,0,0,0},{0,0,0,0}}};
  for (int kt = 0; kt < LSEQ; kt += 64) {
    bf16x8 vb[2];
#pragma unroll
    for (int dt = 0; dt < 2; ++dt)
      vb[dt] = *(const bf16x8*)&Vtb[((size_t)bh * HD + dt * 16 + l15) * LSEQ + kt + sh * 32 + q4 * 8];
#pragma unroll
    for (int s2 = 0; s2 < 2; ++s2) {
      const int st = sh * 2 + s2;
      const int kg = kt + st * 16 + l15;
      const size_t koff = ((size_t)b * LSEQ + kt + st * 16 + l15) * DMODEL + h * HD + q4 * 8;
      bf16x8 kbh = *(const bf16x8*)&Khb[koff];
      bf16x8 kbl = *(const bf16x8*)&Klb[koff];
      float dsum = 0.f;
#pragma unroll
      for (int rg = 0; rg < 2; ++rg) {
        f32x4 s = {0.f, 0.f, 0.f, 0.f};
        s = MFMA(qh[rg], kbh, s, 0, 0, 0);
        s = MFMA(ql[rg], kbh, s, 0, 0, 0);
        s = MFMA(qh[rg], kbl, s, 0, 0, 0);
#pragma unroll
        for (int r = 0; r < 4; ++r) {
          float p = __expf(s[r] * scale) * linv[rg][r];
          int qrow = q0 + qg * 32 + rg * 16 + q4 * 4 + r;
          int dist = (qrow >= kg) ? (qrow - kg) : (kg - qrow);
          dsum += fabsf(p - Elds[dist] * iz[rg][r]);
          Pt[w][rg * 16 + q4 * 4 + r][s2 * 16 + l15] = f2bf(p);
        }
      }
      dsum += __shfl_xor(dsum, 16);
      dsum += __shfl_xor(dsum, 32);
      if (q4 == 0) atomicAdd(&dcol[kg], dsum);
    }
#pragma unroll
    for (int rg = 0; rg < 2; ++rg) {
      bf16x8 pa = *(const bf16x8*)&Pt[w][rg * 16 + l15][q4 * 8];
#pragma unroll
      for (int dt = 0; dt < 2; ++dt)
        oacc[rg][dt] = MFMA(pa, vb[dt], oacc[rg][dt], 0, 0, 0);
    }
  }

  // ---- epilogue: cross-wave-pair O reduce, split-bf16 O store, disc flush ----
  __syncthreads();
  float* Ored = (float*)&Pt[0][0][0];   // 10240B >= 8192B needed
  if (sh == 1) {
#pragma unroll
    for (int rg = 0; rg < 2; ++rg)
#pragma unroll
      for (int dt = 0; dt < 2; ++dt)
#pragma unroll
        for (int r = 0; r < 4; ++r)
          Ored[qg * 1024 + (dt * 16 + l15) * 32 + rg * 16 + q4 * 4 + r] = oacc[rg][dt][r];
  }
  __syncthreads();
  if (sh == 0) {
#pragma unroll
    for (int rg = 0; rg < 2; ++rg)
#pragma unroll
      for (int dt = 0; dt < 2; ++dt)
#pragma unroll
        for (int r = 0; r < 4; ++r) {
          float v = oacc[rg][dt][r] + Ored[qg * 1024 + (dt * 16 + l15) * 32 + rg * 16 + q4 * 4 + r];
          int orow = q0 + qg * 32 + rg * 16 + q4 * 4 + r;
          size_t oo = ((size_t)b * LSEQ + orow) * DMODEL + h * HD + dt * 16 + l15;
          short hi = f2bf(v);
          Ohb[oo] = hi;
          Olb[oo] = f2bf(v - bf2f(hi));
        }
  }
  const float sc = 1.0f / (float)(NH * LSEQ);
  for (int i = tid; i < LSEQ; i += 256)
    atomicAdd(&disc[(size_t)b * LSEQ + i], dcol[i] * sc);
}

extern "C" void kernel_launch(void* const* d_in, const int* in_sizes, int n_in,
                              void* d_out, int out_size, void* d_ws, size_t ws_size,
                              hipStream_t stream)
{
  const float* x  = (const float*)d_in[0];
  const float* Wq = (const float*)d_in[1];
  const float* bq = (const float*)d_in[2];
  const float* Wk = (const float*)d_in[3];
  const float* bk = (const float*)d_in[4];
  const float* Wv = (const float*)d_in[5];
  const float* bv = (const float*)d_in[6];
  const float* u  = (const float*)d_in[7];
  const float* Wo = (const float*)d_in[8];
  const float* bo = (const float*)d_in[9];

  float* out  = (float*)d_out;
  float* disc = out + (size_t)2 * LSEQ * DMODEL;

  char* w8 = (char*)d_ws;
  const size_t MB = 1u << 20;
  short* xh  = (short*)(w8);              // 2MB  (reused as Ohb)
  short* xl  = (short*)(w8 + 2 * MB);     // 2MB  (reused as Olb)
  short* Qhb = (short*)(w8 + 4 * MB);
  short* Qlb = (short*)(w8 + 6 * MB);
  short* Khb = (short*)(w8 + 8 * MB);
  short* Klb = (short*)(w8 + 10 * MB);
  short* Vtb = (short*)(w8 + 12 * MB);
  short* Wch = (short*)(w8 + 14 * MB);
  short* Wcl = (short*)(w8 + 14 * MB + 393216);
  short* Woh = (short*)(w8 + 14 * MB + 786432);
  short* Wol = (short*)(w8 + 14 * MB + 917504);
  float* Eb  = (float*)(w8 + 15 * MB);
  float* Zb  = (float*)(w8 + 15 * MB + 65536);
  short* Ohb = xh;   // x dead after qkv_gemm
  short* Olb = xl;

  hipMemsetAsync(disc, 0, (size_t)2 * LSEQ * sizeof(float), stream);
  convert_kernel<<<1280, 256, 0, stream>>>(x, Wq, Wk, Wv, Wo, xh, xl, Wch, Wcl, Woh, Wol);
  prior_kernel<<<NH, 256, 0, stream>>>(u, Eb, Zb);
  qkv_gemm<<<dim3(64, 12), 256, 0, stream>>>(xh, xl, Wch, Wcl, bq, bk, bv,
                                             Qhb, Qlb, Khb, Klb, Vtb);
  attn_kernel<<<dim3(LSEQ / 64, NH, 2), 256, 0, stream>>>(Qhb, Qlb, Khb, Klb, Vtb,
                                                          Eb, Zb, Ohb, Olb, disc);
  out_gemm<<<dim3(64, 4), 256, 0, stream>>>(Ohb, Olb, Woh, Wol, bo, out);
}